// Round 11
// baseline (1281.964 us; speedup 1.0000x reference)
//
#include <hip/hip_runtime.h>
#include <hip/hip_bf16.h>

typedef unsigned int  u32;
typedef unsigned short u16;
typedef unsigned long long u64;
typedef __attribute__((ext_vector_type(8))) short bf16x8;
typedef __attribute__((ext_vector_type(4))) float f32x4;

#define B_   1024
#define T_   128
#define NBT  (B_*T_)
#define CHUNK 32768
#define NCHUNK 4

// ---- wsb (u16 element offsets) ----
#define WG_OFF   0          // grid_fc [128][2240] bf16, K permuted: k' = pos*32 + ch
#define WT_OFF   286720     // trunk   [128][192]  bf16
#define WIH_OFF  311296     // W_ih    [512][128]  bf16
#define W2_OFF   376832     // conv2   [32][160]   bf16 (tap-pair, tap9=0)
#define W1C_OFF  381952     // conv1   [16][32]    bf16 (taps 0-8 + zeros)
#define CVT_TOTAL 382464

// ---- d_ws byte offsets (ws_size in [256MiB,257MiB)) ----
#define TRUNK_OFF (1ull<<20)      // [T][B][128] bf16 = 33.55 MB
#define H_OFF     (36ull<<20)     // [T][B][128] bf16 = 33.55 MB
#define CTX_OFF   (72ull<<20)     // [BT][64]    bf16 = 16.78 MB
#define C2_OFF    (92ull<<20)     // chunk c2 146.8 MB; REUSED as gates_x [T][512][B] 134.2 MB
#define GX_OFF    C2_OFF

__device__ __forceinline__ u16 f2bf(float f){
  u32 u = __float_as_uint(f);
  u32 r = u + 0x7fffu + ((u >> 16) & 1u);   // RNE
  return (u16)(r >> 16);
}
__device__ __forceinline__ float bf2f(u16 u){ return __uint_as_float((u32)u << 16); }
__device__ __forceinline__ float sigm(float x){ return 1.f / (1.f + __expf(-x)); }
__device__ __forceinline__ float tanh_f(float x){ return 2.f / (1.f + __expf(-2.f*x)) - 1.f; }

__device__ __forceinline__ void bar_lds() {
  __builtin_amdgcn_sched_barrier(0);
  asm volatile("s_waitcnt lgkmcnt(0)" ::: "memory");
  __builtin_amdgcn_s_barrier();
  __builtin_amdgcn_sched_barrier(0);
}

// ---------------------------------------------------------------------------
// K0: weights -> bf16 workspace (unchanged, verified).
// ---------------------------------------------------------------------------
__global__ void k_cvt(const float* __restrict__ gfw, const float* __restrict__ tw,
                      const float* __restrict__ wih, const float* __restrict__ c2w,
                      const float* __restrict__ c1w, u16* __restrict__ wsb) {
  int i = blockIdx.x * 256 + threadIdx.x;
  if (i >= CVT_TOTAL) return;
  float v;
  if (i < WT_OFF) {
    int o = i / 2240; int k = i - o*2240;
    int pos = k >> 5, ch = k & 31;
    v = gfw[o*2240 + ch*70 + pos];
  }
  else if (i < WIH_OFF)  v = tw[i - WT_OFF];
  else if (i < W2_OFF)   v = wih[i - WIH_OFF];
  else if (i < W1C_OFF) {
    int j = i - W2_OFF; int co = j / 160; int k = j - co*160;
    int tap = k >> 4; int ci = k & 15;
    v = (tap < 9) ? c2w[co*144 + ci*9 + tap] : 0.f;
  } else {
    int j = i - W1C_OFF; int ch = j >> 5; int k = j & 31;
    v = (k < 9) ? c1w[ch*9 + k] : 0.f;
  }
  wsb[i] = f2bf(v);
}

// ---------------------------------------------------------------------------
// K1a: conv1 + conv2 + ctx_fc. R11: zero only the 38-position halo of act1
// (608 uint4 instead of 1728; swizzle-consistent addresses).
// ---------------------------------------------------------------------------
__global__ __launch_bounds__(512, 4) void k_conv(
    const float* __restrict__ states,
    const float* __restrict__ c1b, const float* __restrict__ c2b,
    const float* __restrict__ cfw, const float* __restrict__ cfb,
    const u16* __restrict__ wsb,
    u16* __restrict__ c2g,
    u16* __restrict__ ctxg)
{
  __shared__ float s_st[8][96];
  __shared__ __align__(16) u16 act1[8*108*16];
  __shared__ float s_cf[64][25];

  const int tid  = threadIdx.x;
  const int lane = tid & 63;
  const int w    = tid >> 6;
  const int arow = lane & 15;
  const int grp  = lane >> 4;
  const int m0   = blockIdx.x * 8;

  bf16x8 Bc1 = *(const bf16x8*)(wsb + W1C_OFF + arow*32 + grp*8);
  bf16x8 b2f[5][2];
  #pragma unroll
  for (int p = 0; p < 5; p++)
    #pragma unroll
    for (int nt = 0; nt < 2; nt++)
      b2f[p][nt] = *(const bf16x8*)(wsb + W2_OFF + (nt*16 + arow)*160 + p*32 + grp*8);
  float c1bv[4], c2bv0[4], c2bv1[4];
  #pragma unroll
  for (int r = 0; r < 4; r++) {
    c1bv[r]  = c1b[grp*4 + r];
    c2bv0[r] = c2b[grp*4 + r];
    c2bv1[r] = c2b[16 + grp*4 + r];
  }
  const float cfbr = cfb[lane];

  if (tid < 376) {
    float2 v = *(const float2*)(states + (size_t)m0*94 + tid*2);
    int s = (tid*2)/94, c = (tid*2)%94;
    *(float2*)&s_st[s][c] = v;
  }
  // halo-only zero: 8 samples x 38 halo positions x 2 halves = 608 uint4
  for (int i = tid; i < 608; i += 512) {
    int s = i / 76; int r = i - s*76; int hi2 = r >> 1; int h = r & 1;
    int hp;
    if (hi2 < 12)      hp = hi2;                       // y=0 row
    else if (hi2 < 24) hp = 96 + (hi2 - 12);           // y=8 row
    else if (hi2 < 31) hp = (hi2 - 23) * 12;           // x=0 col, y=1..7
    else               hp = (hi2 - 30) * 12 + 11;      // x=11 col, y=1..7
    u32 a = (u32)((s*108 + hp)*32 + h*16) ^ (u32)((hp & 7) << 4);
    *(uint4*)((char*)act1 + a) = (uint4){0,0,0,0};
  }
  for (int i = tid; i < 1536; i += 512) s_cf[i/24][i%24] = cfw[i];
  __syncthreads();

  const bf16x8 zv = {0,0,0,0,0,0,0,0};

  for (int mt = w; mt < 35; mt += 8) {
    int row = mt*16 + arow;
    int s = (int)(((u32)row * 59919u) >> 22); int pos = row - s*70;
    int y = (int)(((u32)pos * 6554u) >> 16);  int x = pos - y*10;
    bf16x8 pf = zv;
    if (grp == 0) {
      const float* gs = &s_st[s][0];
      #pragma unroll
      for (int t = 0; t < 8; t++) {
        int dy = t/3, dx = t - (t/3)*3;
        int yy = y + dy - 1, xx = x + dx - 1;
        bool ok = (yy >= 0) & (yy < 7) & (xx >= 0) & (xx < 10);
        float v = gs[ok ? yy*10 + xx : 0];
        pf[t] = (short)f2bf(ok ? v : 0.f);
      }
    } else if (grp == 1) {
      int yy = y + 1, xx = x + 1;
      bool ok = (yy < 7) & (xx < 10);
      float v = s_st[s][ok ? yy*10 + xx : 0];
      pf[0] = (short)f2bf(ok ? v : 0.f);
    }
    f32x4 acc = __builtin_amdgcn_mfma_f32_16x16x32_bf16(Bc1, pf, (f32x4){0.f,0.f,0.f,0.f}, 0, 0, 0);
    int hp = (y+1)*12 + (x+1);
    u16 q0 = f2bf(fmaxf(acc[0] + c1bv[0], 0.f));
    u16 q1 = f2bf(fmaxf(acc[1] + c1bv[1], 0.f));
    u16 q2 = f2bf(fmaxf(acc[2] + c1bv[2], 0.f));
    u16 q3 = f2bf(fmaxf(acc[3] + c1bv[3], 0.f));
    u64 pk = (u64)q0 | ((u64)q1 << 16) | ((u64)q2 << 32) | ((u64)q3 << 48);
    u32 wa = (u32)(((s*108 + hp)*16 + grp*4)*2) ^ (u32)((hp & 7) << 4);
    *(u64*)((char*)act1 + wa) = pk;
  }
  __syncthreads();

  for (int mt = w; mt < 35; mt += 8) {
    int row = mt*16 + arow;
    int s = (int)(((u32)row * 59919u) >> 22); int pos = row - s*70;
    int y = (int)(((u32)pos * 6554u) >> 16);  int x = pos - y*10;
    f32x4 acc0 = {0.f,0.f,0.f,0.f}, acc1 = {0.f,0.f,0.f,0.f};
    #pragma unroll
    for (int p = 0; p < 5; p++) {
      int tap = p*2 + (grp >> 1); if (tap > 8) tap = 8;
      int dy = (tap * 11) >> 5; int dx = tap - dy*3;
      int hp = (y + dy)*12 + (x + dx);
      u32 ra = (u32)(((s*108 + hp)*16 + (grp & 1)*8)*2) ^ (u32)((hp & 7) << 4);
      bf16x8 bv = *(const bf16x8*)((const char*)act1 + ra);
      acc0 = __builtin_amdgcn_mfma_f32_16x16x32_bf16(b2f[p][0], bv, acc0, 0, 0, 0);
      acc1 = __builtin_amdgcn_mfma_f32_16x16x32_bf16(b2f[p][1], bv, acc1, 0, 0, 0);
    }
    {
      u16 q0 = f2bf(fmaxf(acc0[0] + c2bv0[0], 0.f));
      u16 q1 = f2bf(fmaxf(acc0[1] + c2bv0[1], 0.f));
      u16 q2 = f2bf(fmaxf(acc0[2] + c2bv0[2], 0.f));
      u16 q3 = f2bf(fmaxf(acc0[3] + c2bv0[3], 0.f));
      u64 pk = (u64)q0 | ((u64)q1 << 16) | ((u64)q2 << 32) | ((u64)q3 << 48);
      *(u64*)(c2g + (size_t)(m0 + s)*2240 + pos*32 + grp*4) = pk;
    }
    {
      u16 q0 = f2bf(fmaxf(acc1[0] + c2bv1[0], 0.f));
      u16 q1 = f2bf(fmaxf(acc1[1] + c2bv1[1], 0.f));
      u16 q2 = f2bf(fmaxf(acc1[2] + c2bv1[2], 0.f));
      u16 q3 = f2bf(fmaxf(acc1[3] + c2bv1[3], 0.f));
      u64 pk = (u64)q0 | ((u64)q1 << 16) | ((u64)q2 << 32) | ((u64)q3 << 48);
      *(u64*)(c2g + (size_t)(m0 + s)*2240 + pos*32 + 16 + grp*4) = pk;
    }
  }

  {
    float a = cfbr;
    #pragma unroll
    for (int k = 0; k < 24; k++) a = fmaf(s_cf[lane][k], s_st[w][70 + k], a);
    ctxg[(size_t)(m0 + w)*64 + lane] = f2bf(fmaxf(a, 0.f));
  }
}

// ---------------------------------------------------------------------------
// K1b: grid_fc + ctx + trunk GEMM. R11: 2-deep B register pipe (parked data
// was issued 2 iterations ago -> vmcnt never blocks).
// ---------------------------------------------------------------------------
__global__ __launch_bounds__(512, 4) void k_gemm(
    const u16* __restrict__ c2g, const u16* __restrict__ ctxg,
    const float* __restrict__ gfb, const float* __restrict__ tbv,
    const u16* __restrict__ wsb, u16* __restrict__ trunk_ws, int nbase)
{
  __shared__ __align__(16) u16 s_b[2][128*36];
  __shared__ __align__(16) u16 s_g[128*204];

  const int tid  = threadIdx.x;
  const int lane = tid & 63;
  const int w    = tid >> 6;
  const int arow = lane & 15;
  const int grp  = lane >> 4;
  const int m0   = blockIdx.x * 128;

  float gfbv[8], tbvv[8];
  #pragma unroll
  for (int nt = 0; nt < 8; nt++) {
    gfbv[nt] = gfb[nt*16 + arow];
    tbvv[nt] = tbv[nt*16 + arow];
  }

  const int srow = tid >> 2, sseg = (tid & 3) * 8;
  const u16* wg = wsb + WG_OFF;
  const u16* ap = c2g + (size_t)(m0 + w*16 + arow) * 2240 + grp*8;

  {
    uint4 b0v = *(const uint4*)(wg + (size_t)srow*2240 + sseg);
    *(uint4*)&s_b[0][srow*36 + sseg] = b0v;
  }
  uint4 Bp = *(const uint4*)(wg + (size_t)srow*2240 + 32 + sseg);   // data for ks=1
  bf16x8 a_cur = *(const bf16x8*)(ap);
  bf16x8 a_nxt = *(const bf16x8*)(ap + 32);
  f32x4 acc[8];
  #pragma unroll
  for (int nt = 0; nt < 8; nt++) acc[nt] = (f32x4){0.f,0.f,0.f,0.f};
  __syncthreads();

  #pragma unroll 2
  for (int ks = 0; ks < 70; ks++) {
    uint4 Bn;
    bf16x8 a_fut = a_nxt;
    if (ks < 68) {
      Bn    = *(const uint4*)(wg + (size_t)srow*2240 + (ks+2)*32 + sseg);
      a_fut = *(const bf16x8*)(ap + (size_t)(ks+2)*32);
    }
    const u16* sb = &s_b[ks & 1][0];
    #pragma unroll
    for (int nt = 0; nt < 8; nt++) {
      bf16x8 bv = *(const bf16x8*)&sb[(nt*16 + arow)*36 + grp*8];
      acc[nt] = __builtin_amdgcn_mfma_f32_16x16x32_bf16(a_cur, bv, acc[nt], 0, 0, 0);
    }
    if (ks < 69)
      *(uint4*)&s_b[(ks+1) & 1][srow*36 + sseg] = Bp;
    Bp = Bn;
    a_cur = a_nxt; a_nxt = a_fut;
    bar_lds();
  }

  #pragma unroll
  for (int nt = 0; nt < 8; nt++)
    #pragma unroll
    for (int r = 0; r < 4; r++)
      s_g[(w*16 + grp*4 + r)*204 + nt*16 + arow] = f2bf(fmaxf(acc[nt][r] + gfbv[nt], 0.f));

  {
    int row = tid >> 2, seg = (tid & 3) * 16;
    uint4 c0 = *(const uint4*)(ctxg + (size_t)(m0 + row)*64 + seg);
    uint4 c1 = *(const uint4*)(ctxg + (size_t)(m0 + row)*64 + seg + 8);
    *(uint4*)&s_g[row*204 + 128 + seg]     = c0;
    *(uint4*)&s_g[row*204 + 128 + seg + 8] = c1;
  }
  bar_lds();

  {
    f32x4 tacc[8];
    #pragma unroll
    for (int nt = 0; nt < 8; nt++) tacc[nt] = (f32x4){0.f,0.f,0.f,0.f};
    #pragma unroll
    for (int ks = 0; ks < 6; ks++) {
      bf16x8 av = *(const bf16x8*)&s_g[(w*16 + arow)*204 + ks*32 + grp*8];
      #pragma unroll
      for (int nt = 0; nt < 8; nt++) {
        bf16x8 bv = *(const bf16x8*)(wsb + WT_OFF + (size_t)(nt*16 + arow)*192 + ks*32 + grp*8);
        tacc[nt] = __builtin_amdgcn_mfma_f32_16x16x32_bf16(av, bv, tacc[nt], 0, 0, 0);
      }
    }
    #pragma unroll
    for (int nt = 0; nt < 8; nt++)
      #pragma unroll
      for (int r = 0; r < 4; r++)
        s_g[(w*16 + grp*4 + r)*204 + nt*16 + arow] = f2bf(fmaxf(tacc[nt][r] + tbvv[nt], 0.f));
  }
  bar_lds();

  {
    const int bb = (nbase + m0) >> 7;
    int row = tid >> 2, seg = (tid & 3) * 32;
    #pragma unroll
    for (int j = 0; j < 4; j++) {
      uint4 v = *(const uint4*)&s_g[row*204 + seg + j*8];
      *(uint4*)(trunk_ws + ((size_t)row*B_ + bb)*128 + seg + j*8) = v;
    }
  }
}

// ---------------------------------------------------------------------------
// K1c: gates_x = trunk @ W_ih^T, output [t][gate][b] bf16 (overlays dead c2g).
// 1024 blocks (t x b-chunk of 128), 512 threads. A direct-global, B from L2.
// ---------------------------------------------------------------------------
__global__ __launch_bounds__(512, 2) void k_xg(
    const u16* __restrict__ trunk_ws, const u16* __restrict__ wsb,
    u16* __restrict__ gxg)
{
  const int tid  = threadIdx.x;
  const int lane = tid & 63;
  const int w    = tid >> 6;
  const int arow = lane & 15;
  const int grp  = lane >> 4;
  const int t    = blockIdx.x >> 3;
  const int bch  = (blockIdx.x & 7) * 128;

  bf16x8 av[4];
  #pragma unroll
  for (int ks = 0; ks < 4; ks++)
    av[ks] = *(const bf16x8*)(trunk_ws + ((size_t)t*B_ + bch + w*16 + arow)*128 + ks*32 + grp*8);

  const u16* wip = wsb + WIH_OFF;
  #pragma unroll 1
  for (int ntb = 0; ntb < 32; ntb += 4) {
    f32x4 acc[4];
    #pragma unroll
    for (int q = 0; q < 4; q++) acc[q] = (f32x4){0.f,0.f,0.f,0.f};
    #pragma unroll
    for (int ks = 0; ks < 4; ks++) {
      #pragma unroll
      for (int q = 0; q < 4; q++) {
        bf16x8 bv = *(const bf16x8*)(wip + (size_t)((ntb+q)*16 + arow)*128 + ks*32 + grp*8);
        acc[q] = __builtin_amdgcn_mfma_f32_16x16x32_bf16(av[ks], bv, acc[q], 0, 0, 0);
      }
    }
    #pragma unroll
    for (int q = 0; q < 4; q++) {
      int gate = (ntb+q)*16 + arow;
      u16 q0 = f2bf(acc[q][0]);
      u16 q1 = f2bf(acc[q][1]);
      u16 q2 = f2bf(acc[q][2]);
      u16 q3 = f2bf(acc[q][3]);
      u64 pk = (u64)q0 | ((u64)q1 << 16) | ((u64)q2 << 32) | ((u64)q3 << 48);
      *(u64*)(gxg + ((size_t)t*512 + gate)*1024 + bch + w*16 + grp*4) = pk;
    }
  }
}

// ---------------------------------------------------------------------------
// K2: MFMA LSTM v3. x-path removed (gates_x precomputed); 16 MFMA/wave/step;
// gates_x u64 loads prefetched 2 steps deep; h dbuf + deferred coalesced copy.
// ---------------------------------------------------------------------------
__global__ __launch_bounds__(512, 1) void k_lstm(
    const u16* __restrict__ gxg, const float* __restrict__ whh,
    const float* __restrict__ bih, u16* __restrict__ h_ws)
{
  __shared__ __align__(16) u16 s_h[2][16*136];

  const int tid  = threadIdx.x;
  const int lane = tid & 63;
  const int w    = tid >> 6;
  const int arow = lane & 15;
  const int grp  = lane >> 4;
  const int b0   = blockIdx.x * 16;

  bf16x8 Bv[4][4];
  float bihv[4];
  #pragma unroll
  for (int j = 0; j < 4; j++) {
    const int row = j*128 + w*16 + arow;
    bihv[j] = bih[row];
    #pragma unroll
    for (int ks = 0; ks < 4; ks++) {
      const float* s1 = whh + (size_t)row*128 + ks*32 + grp*8;
      float4 a0 = *(const float4*)s1, a1 = *(const float4*)(s1 + 4);
      bf16x8 t1;
      t1[0]=(short)f2bf(a0.x); t1[1]=(short)f2bf(a0.y); t1[2]=(short)f2bf(a0.z); t1[3]=(short)f2bf(a0.w);
      t1[4]=(short)f2bf(a1.x); t1[5]=(short)f2bf(a1.y); t1[6]=(short)f2bf(a1.z); t1[7]=(short)f2bf(a1.w);
      Bv[j][ks] = t1;
    }
  }

  for (int i = tid; i < 2*16*136; i += 512) ((u16*)s_h)[i] = 0;
  const int prow = tid >> 4, pseg = (tid & 15) * 8;
  __syncthreads();

  const u16* gxb = gxg + (size_t)(w*16 + arow)*1024 + b0 + grp*4;   // + (t*512 + j*128)*1024

  // 2-deep gates_x pipe
  u64 Gc[4], Gn[4];
  #pragma unroll
  for (int j = 0; j < 4; j++) {
    Gc[j] = *(const u64*)(gxb + ((size_t)0*512 + j*128)*1024);
    Gn[j] = *(const u64*)(gxb + ((size_t)1*512 + j*128)*1024);
  }

  float cst[4] = {0.f,0.f,0.f,0.f};

  for (int t = 0; t < T_; t++) {
    const int p = t & 1;

    u64 Gf[4] = {0,0,0,0};
    if (t + 2 < T_) {
      #pragma unroll
      for (int j = 0; j < 4; j++)
        Gf[j] = *(const u64*)(gxb + ((size_t)(t+2)*512 + j*128)*1024);
    }

    // coalesced copy-out of h(t-1) from s_h[p]
    if (t > 0 && tid < 256) {
      uint4 hv = *(const uint4*)&s_h[p][prow*136 + pseg];
      *(uint4*)(h_ws + ((size_t)(t-1)*B_ + b0 + prow)*128 + pseg) = hv;
    }

    f32x4 racc[4];
    #pragma unroll
    for (int j = 0; j < 4; j++) racc[j] = (f32x4){0.f,0.f,0.f,0.f};
    #pragma unroll
    for (int ks = 0; ks < 4; ks++) {
      bf16x8 av = *(const bf16x8*)&s_h[p][arow*136 + ks*32 + grp*8];
      #pragma unroll
      for (int j = 0; j < 4; j++)
        racc[j] = __builtin_amdgcn_mfma_f32_16x16x32_bf16(av, Bv[j][ks], racc[j], 0, 0, 0);
    }

    #pragma unroll
    for (int r = 0; r < 4; r++) {
      float xi = racc[0][r] + __uint_as_float((u32)((Gc[0] >> (16*r)) & 0xffffu) << 16) + bihv[0];
      float xf = racc[1][r] + __uint_as_float((u32)((Gc[1] >> (16*r)) & 0xffffu) << 16) + bihv[1];
      float xg = racc[2][r] + __uint_as_float((u32)((Gc[2] >> (16*r)) & 0xffffu) << 16) + bihv[2];
      float xo = racc[3][r] + __uint_as_float((u32)((Gc[3] >> (16*r)) & 0xffffu) << 16) + bihv[3];
      float I = sigm(xi), F = sigm(xf), O = sigm(xo), G = tanh_f(xg);
      cst[r] = F*cst[r] + I*G;
      float hvv = O * tanh_f(cst[r]);
      s_h[1-p][(grp*4 + r)*136 + w*16 + arow] = f2bf(hvv);
    }

    #pragma unroll
    for (int j = 0; j < 4; j++) { Gc[j] = Gn[j]; if (t + 2 < T_) Gn[j] = Gf[j]; }
    bar_lds();
  }

  if (tid < 256) {
    uint4 hv = *(const uint4*)&s_h[T_ & 1][prow*136 + pseg];
    *(uint4*)(h_ws + ((size_t)(T_-1)*B_ + b0 + prow)*128 + pseg) = hv;
  }
}

// ---------------------------------------------------------------------------
// K3: heads (verbatim — known good).
// ---------------------------------------------------------------------------
__global__ __launch_bounds__(256, 1) void k_heads(
    const u16* __restrict__ h_ws, const int* __restrict__ actions,
    const float* __restrict__ aw, const float* __restrict__ ab,
    const float* __restrict__ cw, const float* __restrict__ cb,
    float* __restrict__ out)
{
  const int tid  = threadIdx.x;
  const int lane = tid & 63;
  const int w    = tid >> 6;
  const int arow = lane & 15;
  const int grp  = lane >> 4;

  bf16x8 Ah[4];
  #pragma unroll
  for (int ks = 0; ks < 4; ks++) {
    bf16x8 v = {0,0,0,0,0,0,0,0};
    if (arow < 4) {
      const float* src = aw + arow*128 + ks*32 + grp*8;
      #pragma unroll
      for (int j = 0; j < 8; j++) v[j] = (short)f2bf(src[j]);
    } else if (arow == 4) {
      const float* src = cw + ks*32 + grp*8;
      #pragma unroll
      for (int j = 0; j < 8; j++) v[j] = (short)f2bf(src[j]);
    }
    Ah[ks] = v;
  }
  const float ab0=ab[0], ab1=ab[1], ab2=ab[2], ab3=ab[3], cb0=cb[0];

  #pragma unroll
  for (int g = 0; g < 4; g++) {
    int m0 = (blockIdx.x*4 + w)*64 + g*16;
    int t  = m0 >> 10; int bb = m0 & 1023;
    f32x4 acc = {0.f,0.f,0.f,0.f};
    #pragma unroll
    for (int ks = 0; ks < 4; ks++) {
      bf16x8 bv = *(const bf16x8*)(h_ws + ((size_t)t*B_ + bb + arow)*128 + ks*32 + grp*8);
      acc = __builtin_amdgcn_mfma_f32_16x16x32_bf16(Ah[ks], bv, acc, 0, 0, 0);
    }
    float cr = __shfl_xor(acc[0], 16);
    if (grp == 0) {
      float L0 = acc[0] + ab0, L1 = acc[1] + ab1, L2 = acc[2] + ab2, L3 = acc[3] + ab3;
      float Lv = cr + cb0;
      float mm = fmaxf(fmaxf(L0, L1), fmaxf(L2, L3));
      float e0 = __expf(L0-mm), e1 = __expf(L1-mm), e2 = __expf(L2-mm), e3 = __expf(L3-mm);
      float S = e0+e1+e2+e3; float lse = __logf(S);
      float p0=L0-mm-lse, p1=L1-mm-lse, p2=L2-mm-lse, p3=L3-mm-lse;
      int n = (bb + arow)*T_ + t;
      int a = actions[n];
      float lpa = (a==0)?p0:(a==1)?p1:(a==2)?p2:p3;
      float ent = -(e0*p0 + e1*p1 + e2*p2 + e3*p3) / S;
      out[n] = lpa; out[NBT + n] = Lv; out[2*NBT + n] = ent;
    }
  }
}

extern "C" void kernel_launch(void* const* d_in, const int* in_sizes, int n_in,
                              void* d_out, int out_size, void* d_ws, size_t ws_size,
                              hipStream_t stream) {
  const float* states = (const float*)d_in[0];
  const int*   actions= (const int*)  d_in[1];
  const float* c1w = (const float*)d_in[2];
  const float* c1b = (const float*)d_in[3];
  const float* c2w = (const float*)d_in[4];
  const float* c2b = (const float*)d_in[5];
  const float* gfw = (const float*)d_in[6];
  const float* gfb = (const float*)d_in[7];
  const float* cfw = (const float*)d_in[8];
  const float* cfb = (const float*)d_in[9];
  const float* tw  = (const float*)d_in[10];
  const float* tbv = (const float*)d_in[11];
  const float* wih = (const float*)d_in[12];
  const float* bih = (const float*)d_in[13];
  const float* whh = (const float*)d_in[14];
  const float* aw  = (const float*)d_in[15];
  const float* ab  = (const float*)d_in[16];
  const float* cw  = (const float*)d_in[17];
  const float* cb  = (const float*)d_in[18];
  float* out = (float*)d_out;

  u16* wsb   = (u16*)d_ws;
  u16* trunk = (u16*)((char*)d_ws + TRUNK_OFF);
  u16* h_ws  = (u16*)((char*)d_ws + H_OFF);
  u16* ctxg  = (u16*)((char*)d_ws + CTX_OFF);
  u16* c2g   = (u16*)((char*)d_ws + C2_OFF);
  u16* gxg   = (u16*)((char*)d_ws + GX_OFF);   // overlays c2g (dead after chunks)

  k_cvt<<<(CVT_TOTAL + 255)/256, 256, 0, stream>>>(gfw, tw, wih, c2w, c1w, wsb);

  for (int c = 0; c < NCHUNK; c++) {
    const float* st_c = states + (size_t)c * CHUNK * 94;
    u16* ctx_c = ctxg + (size_t)c * CHUNK * 64;
    k_conv<<<CHUNK/8, 512, 0, stream>>>(st_c, c1b, c2b, cfw, cfb, wsb, c2g, ctx_c);
    k_gemm<<<CHUNK/128, 512, 0, stream>>>(c2g, ctx_c, gfb, tbv, wsb, trunk, c*CHUNK);
  }
  k_xg<<<T_*8, 512, 0, stream>>>(trunk, wsb, gxg);
  k_lstm<<<B_/16, 512, 0, stream>>>(gxg, whh, bih, h_ws);
  k_heads<<<512, 256, 0, stream>>>(h_ws, actions, aw, ab, cw, cb, out);
}

// Round 12
// 1209.317 us; speedup vs baseline: 1.0601x; 1.0601x over previous
//
#include <hip/hip_runtime.h>
#include <hip/hip_bf16.h>

typedef unsigned int  u32;
typedef unsigned short u16;
typedef unsigned long long u64;
typedef __attribute__((ext_vector_type(8))) short bf16x8;
typedef __attribute__((ext_vector_type(4))) float f32x4;

#define B_   1024
#define T_   128
#define NBT  (B_*T_)
#define CHUNK 32768
#define NCHUNK 4

// ---- wsb (u16 element offsets) ----
#define WG_OFF   0          // grid_fc [128][2240] bf16, K permuted: k' = pos*32 + ch
#define WT_OFF   286720     // trunk   [128][192]  bf16
#define WIH_OFF  311296     // W_ih    [512][128]  bf16
#define W2_OFF   376832     // conv2   [32][160]   bf16 (tap-pair, tap9=0)
#define W1C_OFF  381952     // conv1   [16][32]    bf16 (taps 0-8 + zeros)
#define CVT_TOTAL 382464

// ---- d_ws byte offsets (ws_size in [256MiB,257MiB)) ----
#define TRUNK_OFF (1ull<<20)      // [T][B][128] bf16 = 33.55 MB
#define H_OFF     (36ull<<20)     // [T][B][128] bf16 = 33.55 MB
#define CTX_OFF   (72ull<<20)     // [BT][64]    bf16 = 16.78 MB
#define C2_OFF    (92ull<<20)     // chunk c2 146.8 MB; REUSED as gates_x [T][B][512] 134.2 MB
#define GX_OFF    C2_OFF

__device__ __forceinline__ u16 f2bf(float f){
  u32 u = __float_as_uint(f);
  u32 r = u + 0x7fffu + ((u >> 16) & 1u);   // RNE
  return (u16)(r >> 16);
}
__device__ __forceinline__ float bf2f(u16 u){ return __uint_as_float((u32)u << 16); }
__device__ __forceinline__ float sigm(float x){ return 1.f / (1.f + __expf(-x)); }
__device__ __forceinline__ float tanh_f(float x){ return 2.f / (1.f + __expf(-2.f*x)) - 1.f; }

__device__ __forceinline__ void bar_lds() {
  __builtin_amdgcn_sched_barrier(0);
  asm volatile("s_waitcnt lgkmcnt(0)" ::: "memory");
  __builtin_amdgcn_s_barrier();
  __builtin_amdgcn_sched_barrier(0);
}

// ---------------------------------------------------------------------------
// K0: weights -> bf16 workspace (unchanged, verified).
// ---------------------------------------------------------------------------
__global__ void k_cvt(const float* __restrict__ gfw, const float* __restrict__ tw,
                      const float* __restrict__ wih, const float* __restrict__ c2w,
                      const float* __restrict__ c1w, u16* __restrict__ wsb) {
  int i = blockIdx.x * 256 + threadIdx.x;
  if (i >= CVT_TOTAL) return;
  float v;
  if (i < WT_OFF) {
    int o = i / 2240; int k = i - o*2240;
    int pos = k >> 5, ch = k & 31;
    v = gfw[o*2240 + ch*70 + pos];
  }
  else if (i < WIH_OFF)  v = tw[i - WT_OFF];
  else if (i < W2_OFF)   v = wih[i - WIH_OFF];
  else if (i < W1C_OFF) {
    int j = i - W2_OFF; int co = j / 160; int k = j - co*160;
    int tap = k >> 4; int ci = k & 15;
    v = (tap < 9) ? c2w[co*144 + ci*9 + tap] : 0.f;
  } else {
    int j = i - W1C_OFF; int ch = j >> 5; int k = j & 31;
    v = (k < 9) ? c1w[ch*9 + k] : 0.f;
  }
  wsb[i] = f2bf(v);
}

// ---------------------------------------------------------------------------
// K1a: conv1 + conv2 + ctx_fc (verbatim R11 — halo-only zero).
// ---------------------------------------------------------------------------
__global__ __launch_bounds__(512, 4) void k_conv(
    const float* __restrict__ states,
    const float* __restrict__ c1b, const float* __restrict__ c2b,
    const float* __restrict__ cfw, const float* __restrict__ cfb,
    const u16* __restrict__ wsb,
    u16* __restrict__ c2g,
    u16* __restrict__ ctxg)
{
  __shared__ float s_st[8][96];
  __shared__ __align__(16) u16 act1[8*108*16];
  __shared__ float s_cf[64][25];

  const int tid  = threadIdx.x;
  const int lane = tid & 63;
  const int w    = tid >> 6;
  const int arow = lane & 15;
  const int grp  = lane >> 4;
  const int m0   = blockIdx.x * 8;

  bf16x8 Bc1 = *(const bf16x8*)(wsb + W1C_OFF + arow*32 + grp*8);
  bf16x8 b2f[5][2];
  #pragma unroll
  for (int p = 0; p < 5; p++)
    #pragma unroll
    for (int nt = 0; nt < 2; nt++)
      b2f[p][nt] = *(const bf16x8*)(wsb + W2_OFF + (nt*16 + arow)*160 + p*32 + grp*8);
  float c1bv[4], c2bv0[4], c2bv1[4];
  #pragma unroll
  for (int r = 0; r < 4; r++) {
    c1bv[r]  = c1b[grp*4 + r];
    c2bv0[r] = c2b[grp*4 + r];
    c2bv1[r] = c2b[16 + grp*4 + r];
  }
  const float cfbr = cfb[lane];

  if (tid < 376) {
    float2 v = *(const float2*)(states + (size_t)m0*94 + tid*2);
    int s = (tid*2)/94, c = (tid*2)%94;
    *(float2*)&s_st[s][c] = v;
  }
  for (int i = tid; i < 608; i += 512) {
    int s = i / 76; int r = i - s*76; int hi2 = r >> 1; int h = r & 1;
    int hp;
    if (hi2 < 12)      hp = hi2;
    else if (hi2 < 24) hp = 96 + (hi2 - 12);
    else if (hi2 < 31) hp = (hi2 - 23) * 12;
    else               hp = (hi2 - 30) * 12 + 11;
    u32 a = (u32)((s*108 + hp)*32 + h*16) ^ (u32)((hp & 7) << 4);
    *(uint4*)((char*)act1 + a) = (uint4){0,0,0,0};
  }
  for (int i = tid; i < 1536; i += 512) s_cf[i/24][i%24] = cfw[i];
  __syncthreads();

  const bf16x8 zv = {0,0,0,0,0,0,0,0};

  for (int mt = w; mt < 35; mt += 8) {
    int row = mt*16 + arow;
    int s = (int)(((u32)row * 59919u) >> 22); int pos = row - s*70;
    int y = (int)(((u32)pos * 6554u) >> 16);  int x = pos - y*10;
    bf16x8 pf = zv;
    if (grp == 0) {
      const float* gs = &s_st[s][0];
      #pragma unroll
      for (int t = 0; t < 8; t++) {
        int dy = t/3, dx = t - (t/3)*3;
        int yy = y + dy - 1, xx = x + dx - 1;
        bool ok = (yy >= 0) & (yy < 7) & (xx >= 0) & (xx < 10);
        float v = gs[ok ? yy*10 + xx : 0];
        pf[t] = (short)f2bf(ok ? v : 0.f);
      }
    } else if (grp == 1) {
      int yy = y + 1, xx = x + 1;
      bool ok = (yy < 7) & (xx < 10);
      float v = s_st[s][ok ? yy*10 + xx : 0];
      pf[0] = (short)f2bf(ok ? v : 0.f);
    }
    f32x4 acc = __builtin_amdgcn_mfma_f32_16x16x32_bf16(Bc1, pf, (f32x4){0.f,0.f,0.f,0.f}, 0, 0, 0);
    int hp = (y+1)*12 + (x+1);
    u16 q0 = f2bf(fmaxf(acc[0] + c1bv[0], 0.f));
    u16 q1 = f2bf(fmaxf(acc[1] + c1bv[1], 0.f));
    u16 q2 = f2bf(fmaxf(acc[2] + c1bv[2], 0.f));
    u16 q3 = f2bf(fmaxf(acc[3] + c1bv[3], 0.f));
    u64 pk = (u64)q0 | ((u64)q1 << 16) | ((u64)q2 << 32) | ((u64)q3 << 48);
    u32 wa = (u32)(((s*108 + hp)*16 + grp*4)*2) ^ (u32)((hp & 7) << 4);
    *(u64*)((char*)act1 + wa) = pk;
  }
  __syncthreads();

  for (int mt = w; mt < 35; mt += 8) {
    int row = mt*16 + arow;
    int s = (int)(((u32)row * 59919u) >> 22); int pos = row - s*70;
    int y = (int)(((u32)pos * 6554u) >> 16);  int x = pos - y*10;
    f32x4 acc0 = {0.f,0.f,0.f,0.f}, acc1 = {0.f,0.f,0.f,0.f};
    #pragma unroll
    for (int p = 0; p < 5; p++) {
      int tap = p*2 + (grp >> 1); if (tap > 8) tap = 8;
      int dy = (tap * 11) >> 5; int dx = tap - dy*3;
      int hp = (y + dy)*12 + (x + dx);
      u32 ra = (u32)(((s*108 + hp)*16 + (grp & 1)*8)*2) ^ (u32)((hp & 7) << 4);
      bf16x8 bv = *(const bf16x8*)((const char*)act1 + ra);
      acc0 = __builtin_amdgcn_mfma_f32_16x16x32_bf16(b2f[p][0], bv, acc0, 0, 0, 0);
      acc1 = __builtin_amdgcn_mfma_f32_16x16x32_bf16(b2f[p][1], bv, acc1, 0, 0, 0);
    }
    {
      u16 q0 = f2bf(fmaxf(acc0[0] + c2bv0[0], 0.f));
      u16 q1 = f2bf(fmaxf(acc0[1] + c2bv0[1], 0.f));
      u16 q2 = f2bf(fmaxf(acc0[2] + c2bv0[2], 0.f));
      u16 q3 = f2bf(fmaxf(acc0[3] + c2bv0[3], 0.f));
      u64 pk = (u64)q0 | ((u64)q1 << 16) | ((u64)q2 << 32) | ((u64)q3 << 48);
      *(u64*)(c2g + (size_t)(m0 + s)*2240 + pos*32 + grp*4) = pk;
    }
    {
      u16 q0 = f2bf(fmaxf(acc1[0] + c2bv1[0], 0.f));
      u16 q1 = f2bf(fmaxf(acc1[1] + c2bv1[1], 0.f));
      u16 q2 = f2bf(fmaxf(acc1[2] + c2bv1[2], 0.f));
      u16 q3 = f2bf(fmaxf(acc1[3] + c2bv1[3], 0.f));
      u64 pk = (u64)q0 | ((u64)q1 << 16) | ((u64)q2 << 32) | ((u64)q3 << 48);
      *(u64*)(c2g + (size_t)(m0 + s)*2240 + pos*32 + 16 + grp*4) = pk;
    }
  }

  {
    float a = cfbr;
    #pragma unroll
    for (int k = 0; k < 24; k++) a = fmaf(s_cf[lane][k], s_st[w][70 + k], a);
    ctxg[(size_t)(m0 + w)*64 + lane] = f2bf(fmaxf(a, 0.f));
  }
}

// ---------------------------------------------------------------------------
// K1b: grid_fc + ctx + trunk GEMM (reverted to R10-exact — known good).
// ---------------------------------------------------------------------------
__global__ __launch_bounds__(512, 4) void k_gemm(
    const u16* __restrict__ c2g, const u16* __restrict__ ctxg,
    const float* __restrict__ gfb, const float* __restrict__ tbv,
    const u16* __restrict__ wsb, u16* __restrict__ trunk_ws, int nbase)
{
  __shared__ __align__(16) u16 s_b[2][128*36];
  __shared__ __align__(16) u16 s_g[128*204];

  const int tid  = threadIdx.x;
  const int lane = tid & 63;
  const int w    = tid >> 6;
  const int arow = lane & 15;
  const int grp  = lane >> 4;
  const int m0   = blockIdx.x * 128;

  float gfbv[8], tbvv[8];
  #pragma unroll
  for (int nt = 0; nt < 8; nt++) {
    gfbv[nt] = gfb[nt*16 + arow];
    tbvv[nt] = tbv[nt*16 + arow];
  }

  const int srow = tid >> 2, sseg = (tid & 3) * 8;
  const u16* wg = wsb + WG_OFF;
  const u16* ap = c2g + (size_t)(m0 + w*16 + arow) * 2240 + grp*8;

  {
    uint4 b0 = *(const uint4*)(wg + (size_t)srow*2240 + sseg);
    *(uint4*)&s_b[0][srow*36 + sseg] = b0;
  }
  bf16x8 a_cur = *(const bf16x8*)(ap);
  bf16x8 a_nxt = *(const bf16x8*)(ap + 32);
  f32x4 acc[8];
  #pragma unroll
  for (int nt = 0; nt < 8; nt++) acc[nt] = (f32x4){0.f,0.f,0.f,0.f};
  __syncthreads();

  #pragma unroll 2
  for (int ks = 0; ks < 70; ks++) {
    uint4 bnew;
    if (ks < 69)
      bnew = *(const uint4*)(wg + (size_t)srow*2240 + (ks+1)*32 + sseg);
    bf16x8 a_fut = a_nxt;
    if (ks < 68)
      a_fut = *(const bf16x8*)(ap + (size_t)(ks+2)*32);
    const u16* sb = &s_b[ks & 1][0];
    #pragma unroll
    for (int nt = 0; nt < 8; nt++) {
      bf16x8 bv = *(const bf16x8*)&sb[(nt*16 + arow)*36 + grp*8];
      acc[nt] = __builtin_amdgcn_mfma_f32_16x16x32_bf16(a_cur, bv, acc[nt], 0, 0, 0);
    }
    if (ks < 69)
      *(uint4*)&s_b[(ks+1) & 1][srow*36 + sseg] = bnew;
    a_cur = a_nxt; a_nxt = a_fut;
    bar_lds();
  }

  #pragma unroll
  for (int nt = 0; nt < 8; nt++)
    #pragma unroll
    for (int r = 0; r < 4; r++)
      s_g[(w*16 + grp*4 + r)*204 + nt*16 + arow] = f2bf(fmaxf(acc[nt][r] + gfbv[nt], 0.f));

  {
    int row = tid >> 2, seg = (tid & 3) * 16;
    uint4 c0 = *(const uint4*)(ctxg + (size_t)(m0 + row)*64 + seg);
    uint4 c1 = *(const uint4*)(ctxg + (size_t)(m0 + row)*64 + seg + 8);
    *(uint4*)&s_g[row*204 + 128 + seg]     = c0;
    *(uint4*)&s_g[row*204 + 128 + seg + 8] = c1;
  }
  bar_lds();

  {
    f32x4 tacc[8];
    #pragma unroll
    for (int nt = 0; nt < 8; nt++) tacc[nt] = (f32x4){0.f,0.f,0.f,0.f};
    #pragma unroll
    for (int ks = 0; ks < 6; ks++) {
      bf16x8 av = *(const bf16x8*)&s_g[(w*16 + arow)*204 + ks*32 + grp*8];
      #pragma unroll
      for (int nt = 0; nt < 8; nt++) {
        bf16x8 bv = *(const bf16x8*)(wsb + WT_OFF + (size_t)(nt*16 + arow)*192 + ks*32 + grp*8);
        tacc[nt] = __builtin_amdgcn_mfma_f32_16x16x32_bf16(av, bv, tacc[nt], 0, 0, 0);
      }
    }
    #pragma unroll
    for (int nt = 0; nt < 8; nt++)
      #pragma unroll
      for (int r = 0; r < 4; r++)
        s_g[(w*16 + grp*4 + r)*204 + nt*16 + arow] = f2bf(fmaxf(tacc[nt][r] + tbvv[nt], 0.f));
  }
  bar_lds();

  {
    const int bb = (nbase + m0) >> 7;
    int row = tid >> 2, seg = (tid & 3) * 32;
    #pragma unroll
    for (int j = 0; j < 4; j++) {
      uint4 v = *(const uint4*)&s_g[row*204 + seg + j*8];
      *(uint4*)(trunk_ws + ((size_t)row*B_ + bb)*128 + seg + j*8) = v;
    }
  }
}

// ---------------------------------------------------------------------------
// K1c: gates_x = trunk @ W_ih^T, SWAPPED operands (k_heads-verified mapping):
// lane arow = sample, acc[r] = 4 CONTIGUOUS gates -> u64 stores, layout
// [t][b][512] (coalesced reads in k_lstm). Overlays dead c2g.
// ---------------------------------------------------------------------------
__global__ __launch_bounds__(512, 2) void k_xg(
    const u16* __restrict__ trunk_ws, const u16* __restrict__ wsb,
    u16* __restrict__ gxg)
{
  const int tid  = threadIdx.x;
  const int lane = tid & 63;
  const int w    = tid >> 6;
  const int arow = lane & 15;
  const int grp  = lane >> 4;
  const int t    = blockIdx.x >> 3;
  const int bch  = (blockIdx.x & 7) * 128;
  const int samp = bch + w*16 + arow;

  // B-frag: trunk of this wave's 16 samples
  bf16x8 bv[4];
  #pragma unroll
  for (int ks = 0; ks < 4; ks++)
    bv[ks] = *(const bf16x8*)(trunk_ws + ((size_t)t*B_ + samp)*128 + ks*32 + grp*8);

  const u16* wip = wsb + WIH_OFF;
  u16* gout = gxg + ((size_t)t*B_ + samp)*512;

  #pragma unroll 1
  for (int ntb = 0; ntb < 32; ntb += 4) {
    f32x4 acc[4];
    #pragma unroll
    for (int q = 0; q < 4; q++) acc[q] = (f32x4){0.f,0.f,0.f,0.f};
    #pragma unroll
    for (int ks = 0; ks < 4; ks++) {
      #pragma unroll
      for (int q = 0; q < 4; q++) {
        bf16x8 aw = *(const bf16x8*)(wip + (size_t)((ntb+q)*16 + arow)*128 + ks*32 + grp*8);
        acc[q] = __builtin_amdgcn_mfma_f32_16x16x32_bf16(aw, bv[ks], acc[q], 0, 0, 0);
      }
    }
    #pragma unroll
    for (int q = 0; q < 4; q++) {
      // lane holds gates (ntb+q)*16 + grp*4 + 0..3 of sample `samp`
      u16 q0 = f2bf(acc[q][0]);
      u16 q1 = f2bf(acc[q][1]);
      u16 q2 = f2bf(acc[q][2]);
      u16 q3 = f2bf(acc[q][3]);
      u64 pk = (u64)q0 | ((u64)q1 << 16) | ((u64)q2 << 32) | ((u64)q3 << 48);
      *(u64*)(gout + (ntb+q)*16 + grp*4) = pk;
    }
  }
}

// ---------------------------------------------------------------------------
// K2: MFMA LSTM v4. 256 blocks x 4 samples x 512 threads (ALL CUs).
// Gate redistribution via 8 KB s_g: grp0 lanes scatter valid gates; every
// thread then computes exactly ONE cell (trans-ops/wave 40 -> 10).
// ---------------------------------------------------------------------------
__global__ __launch_bounds__(512, 1) void k_lstm(
    const u16* __restrict__ gxg, const float* __restrict__ whh,
    const float* __restrict__ bih, u16* __restrict__ h_ws)
{
  __shared__ __align__(16) u16 s_h[2][16*136];   // rows 4..15 stay zero
  __shared__ float s_g[4][516];                  // [sample][gate]

  const int tid  = threadIdx.x;
  const int lane = tid & 63;
  const int w    = tid >> 6;
  const int arow = lane & 15;
  const int grp  = lane >> 4;
  const int b0   = blockIdx.x * 4;

  // W_hh B-fragments: rows j*128 + w*16 + arow
  bf16x8 Bv[4][4];
  #pragma unroll
  for (int j = 0; j < 4; j++) {
    const int row = j*128 + w*16 + arow;
    #pragma unroll
    for (int ks = 0; ks < 4; ks++) {
      const float* s1 = whh + (size_t)row*128 + ks*32 + grp*8;
      float4 a0 = *(const float4*)s1, a1 = *(const float4*)(s1 + 4);
      bf16x8 t1;
      t1[0]=(short)f2bf(a0.x); t1[1]=(short)f2bf(a0.y); t1[2]=(short)f2bf(a0.z); t1[3]=(short)f2bf(a0.w);
      t1[4]=(short)f2bf(a1.x); t1[5]=(short)f2bf(a1.y); t1[6]=(short)f2bf(a1.z); t1[7]=(short)f2bf(a1.w);
      Bv[j][ks] = t1;
    }
  }

  for (int i = tid; i < 2*16*136; i += 512) ((u16*)s_h)[i] = 0;

  // cell mapping: 1 cell/thread
  const int cs = tid >> 7;        // sample 0..3
  const int ch = tid & 127;       // h index
  float bihc[4];
  #pragma unroll
  for (int j = 0; j < 4; j++) bihc[j] = bih[j*128 + ch];

  const u16* gxb = gxg + ((size_t)b0 + cs)*512 + ch;   // + t*B*512 + j*128
  u16 Gc[4], Gn[4];
  #pragma unroll
  for (int j = 0; j < 4; j++) {
    Gc[j] = gxb[(size_t)0*B_*512 + j*128];
    Gn[j] = gxb[(size_t)1*B_*512 + j*128];
  }

  const int prow = tid >> 4, pseg = (tid & 15) * 8;    // tid<64 copy-out
  float cst = 0.f;
  __syncthreads();

  for (int t = 0; t < T_; t++) {
    const int p = t & 1;

    // prefetch gates(t+2)
    u16 Gf[4] = {0,0,0,0};
    if (t + 2 < T_) {
      #pragma unroll
      for (int j = 0; j < 4; j++)
        Gf[j] = gxb[(size_t)(t+2)*B_*512 + j*128];
    }
    // coalesced copy-out h(t-1)
    if (t > 0 && tid < 64) {
      uint4 hv = *(const uint4*)&s_h[p][prow*136 + pseg];
      *(uint4*)(h_ws + ((size_t)(t-1)*B_ + b0 + prow)*128 + pseg) = hv;
    }

    // recurrent MFMA (rows 4..15 of s_h are zero)
    f32x4 racc[4];
    #pragma unroll
    for (int j = 0; j < 4; j++) racc[j] = (f32x4){0.f,0.f,0.f,0.f};
    #pragma unroll
    for (int ks = 0; ks < 4; ks++) {
      bf16x8 av = *(const bf16x8*)&s_h[p][arow*136 + ks*32 + grp*8];
      #pragma unroll
      for (int j = 0; j < 4; j++)
        racc[j] = __builtin_amdgcn_mfma_f32_16x16x32_bf16(av, Bv[j][ks], racc[j], 0, 0, 0);
    }
    // redistribute valid gates (samples 0..3 live in grp0 lanes)
    if (grp == 0) {
      #pragma unroll
      for (int j = 0; j < 4; j++)
        #pragma unroll
        for (int r = 0; r < 4; r++)
          s_g[r][j*128 + w*16 + arow] = racc[j][r];
    }
    bar_lds();

    // one cell per thread
    {
      float xi = s_g[cs][ch]       + bf2f(Gc[0]) + bihc[0];
      float xf = s_g[cs][128 + ch] + bf2f(Gc[1]) + bihc[1];
      float xg = s_g[cs][256 + ch] + bf2f(Gc[2]) + bihc[2];
      float xo = s_g[cs][384 + ch] + bf2f(Gc[3]) + bihc[3];
      float I = sigm(xi), F = sigm(xf), O = sigm(xo), G = tanh_f(xg);
      cst = F*cst + I*G;
      float hvv = O * tanh_f(cst);
      s_h[1-p][cs*136 + ch] = f2bf(hvv);
    }

    #pragma unroll
    for (int j = 0; j < 4; j++) { Gc[j] = Gn[j]; Gn[j] = Gf[j]; }
    bar_lds();
  }

  if (tid < 64) {
    uint4 hv = *(const uint4*)&s_h[T_ & 1][prow*136 + pseg];
    *(uint4*)(h_ws + ((size_t)(T_-1)*B_ + b0 + prow)*128 + pseg) = hv;
  }
}

// ---------------------------------------------------------------------------
// K3: heads (verbatim — known good).
// ---------------------------------------------------------------------------
__global__ __launch_bounds__(256, 1) void k_heads(
    const u16* __restrict__ h_ws, const int* __restrict__ actions,
    const float* __restrict__ aw, const float* __restrict__ ab,
    const float* __restrict__ cw, const float* __restrict__ cb,
    float* __restrict__ out)
{
  const int tid  = threadIdx.x;
  const int lane = tid & 63;
  const int w    = tid >> 6;
  const int arow = lane & 15;
  const int grp  = lane >> 4;

  bf16x8 Ah[4];
  #pragma unroll
  for (int ks = 0; ks < 4; ks++) {
    bf16x8 v = {0,0,0,0,0,0,0,0};
    if (arow < 4) {
      const float* src = aw + arow*128 + ks*32 + grp*8;
      #pragma unroll
      for (int j = 0; j < 8; j++) v[j] = (short)f2bf(src[j]);
    } else if (arow == 4) {
      const float* src = cw + ks*32 + grp*8;
      #pragma unroll
      for (int j = 0; j < 8; j++) v[j] = (short)f2bf(src[j]);
    }
    Ah[ks] = v;
  }
  const float ab0=ab[0], ab1=ab[1], ab2=ab[2], ab3=ab[3], cb0=cb[0];

  #pragma unroll
  for (int g = 0; g < 4; g++) {
    int m0 = (blockIdx.x*4 + w)*64 + g*16;
    int t  = m0 >> 10; int bb = m0 & 1023;
    f32x4 acc = {0.f,0.f,0.f,0.f};
    #pragma unroll
    for (int ks = 0; ks < 4; ks++) {
      bf16x8 bv = *(const bf16x8*)(h_ws + ((size_t)t*B_ + bb + arow)*128 + ks*32 + grp*8);
      acc = __builtin_amdgcn_mfma_f32_16x16x32_bf16(Ah[ks], bv, acc, 0, 0, 0);
    }
    float cr = __shfl_xor(acc[0], 16);
    if (grp == 0) {
      float L0 = acc[0] + ab0, L1 = acc[1] + ab1, L2 = acc[2] + ab2, L3 = acc[3] + ab3;
      float Lv = cr + cb0;
      float mm = fmaxf(fmaxf(L0, L1), fmaxf(L2, L3));
      float e0 = __expf(L0-mm), e1 = __expf(L1-mm), e2 = __expf(L2-mm), e3 = __expf(L3-mm);
      float S = e0+e1+e2+e3; float lse = __logf(S);
      float p0=L0-mm-lse, p1=L1-mm-lse, p2=L2-mm-lse, p3=L3-mm-lse;
      int n = (bb + arow)*T_ + t;
      int a = actions[n];
      float lpa = (a==0)?p0:(a==1)?p1:(a==2)?p2:p3;
      float ent = -(e0*p0 + e1*p1 + e2*p2 + e3*p3) / S;
      out[n] = lpa; out[NBT + n] = Lv; out[2*NBT + n] = ent;
    }
  }
}

extern "C" void kernel_launch(void* const* d_in, const int* in_sizes, int n_in,
                              void* d_out, int out_size, void* d_ws, size_t ws_size,
                              hipStream_t stream) {
  const float* states = (const float*)d_in[0];
  const int*   actions= (const int*)  d_in[1];
  const float* c1w = (const float*)d_in[2];
  const float* c1b = (const float*)d_in[3];
  const float* c2w = (const float*)d_in[4];
  const float* c2b = (const float*)d_in[5];
  const float* gfw = (const float*)d_in[6];
  const float* gfb = (const float*)d_in[7];
  const float* cfw = (const float*)d_in[8];
  const float* cfb = (const float*)d_in[9];
  const float* tw  = (const float*)d_in[10];
  const float* tbv = (const float*)d_in[11];
  const float* wih = (const float*)d_in[12];
  const float* bih = (const float*)d_in[13];
  const float* whh = (const float*)d_in[14];
  const float* aw  = (const float*)d_in[15];
  const float* ab  = (const float*)d_in[16];
  const float* cw  = (const float*)d_in[17];
  const float* cb  = (const float*)d_in[18];
  float* out = (float*)d_out;

  u16* wsb   = (u16*)d_ws;
  u16* trunk = (u16*)((char*)d_ws + TRUNK_OFF);
  u16* h_ws  = (u16*)((char*)d_ws + H_OFF);
  u16* ctxg  = (u16*)((char*)d_ws + CTX_OFF);
  u16* c2g   = (u16*)((char*)d_ws + C2_OFF);
  u16* gxg   = (u16*)((char*)d_ws + GX_OFF);

  k_cvt<<<(CVT_TOTAL + 255)/256, 256, 0, stream>>>(gfw, tw, wih, c2w, c1w, wsb);

  for (int c = 0; c < NCHUNK; c++) {
    const float* st_c = states + (size_t)c * CHUNK * 94;
    u16* ctx_c = ctxg + (size_t)c * CHUNK * 64;
    k_conv<<<CHUNK/8, 512, 0, stream>>>(st_c, c1b, c2b, cfw, cfb, wsb, c2g, ctx_c);
    k_gemm<<<CHUNK/128, 512, 0, stream>>>(c2g, ctx_c, gfb, tbv, wsb, trunk, c*CHUNK);
  }
  k_xg<<<T_*8, 512, 0, stream>>>(trunk, wsb, gxg);
  k_lstm<<<B_/4, 512, 0, stream>>>(gxg, whh, bih, h_ws);
  k_heads<<<512, 256, 0, stream>>>(h_ws, actions, aw, ab, cw, cb, out);
}

// Round 13
// 1187.171 us; speedup vs baseline: 1.0798x; 1.0187x over previous
//
#include <hip/hip_runtime.h>
#include <hip/hip_bf16.h>

typedef unsigned int  u32;
typedef unsigned short u16;
typedef unsigned long long u64;
typedef __attribute__((ext_vector_type(8))) short bf16x8;
typedef __attribute__((ext_vector_type(4))) float f32x4;

#define B_   1024
#define T_   128
#define NBT  (B_*T_)
#define CHUNK 32768
#define NCHUNK 4

// ---- wsb (u16 element offsets) ----
#define WG_OFF   0
#define WT_OFF   286720
#define WIH_OFF  311296
#define W2_OFF   376832
#define W1C_OFF  381952
#define CVT_TOTAL 382464

// ---- d_ws byte offsets ----
#define TRUNK_OFF (1ull<<20)
#define H_OFF     (36ull<<20)
#define CTX_OFF   (72ull<<20)
#define C2_OFF    (92ull<<20)
#define GX_OFF    C2_OFF

__device__ __forceinline__ u16 f2bf(float f){
  u32 u = __float_as_uint(f);
  u32 r = u + 0x7fffu + ((u >> 16) & 1u);
  return (u16)(r >> 16);
}
__device__ __forceinline__ float bf2f(u16 u){ return __uint_as_float((u32)u << 16); }
__device__ __forceinline__ float sigm(float x){ return 1.f / (1.f + __expf(-x)); }
__device__ __forceinline__ float tanh_f(float x){ return 2.f / (1.f + __expf(-2.f*x)) - 1.f; }

__device__ __forceinline__ void bar_lds() {
  __builtin_amdgcn_sched_barrier(0);
  asm volatile("s_waitcnt lgkmcnt(0)" ::: "memory");
  __builtin_amdgcn_s_barrier();
  __builtin_amdgcn_sched_barrier(0);
}

// ---------------------------------------------------------------------------
// K0 (verbatim)
// ---------------------------------------------------------------------------
__global__ void k_cvt(const float* __restrict__ gfw, const float* __restrict__ tw,
                      const float* __restrict__ wih, const float* __restrict__ c2w,
                      const float* __restrict__ c1w, u16* __restrict__ wsb) {
  int i = blockIdx.x * 256 + threadIdx.x;
  if (i >= CVT_TOTAL) return;
  float v;
  if (i < WT_OFF) {
    int o = i / 2240; int k = i - o*2240;
    int pos = k >> 5, ch = k & 31;
    v = gfw[o*2240 + ch*70 + pos];
  }
  else if (i < WIH_OFF)  v = tw[i - WT_OFF];
  else if (i < W2_OFF)   v = wih[i - WIH_OFF];
  else if (i < W1C_OFF) {
    int j = i - W2_OFF; int co = j / 160; int k = j - co*160;
    int tap = k >> 4; int ci = k & 15;
    v = (tap < 9) ? c2w[co*144 + ci*9 + tap] : 0.f;
  } else {
    int j = i - W1C_OFF; int ch = j >> 5; int k = j & 31;
    v = (k < 9) ? c1w[ch*9 + k] : 0.f;
  }
  wsb[i] = f2bf(v);
}

// ---------------------------------------------------------------------------
// K1a: conv (verbatim R12)
// ---------------------------------------------------------------------------
__global__ __launch_bounds__(512, 4) void k_conv(
    const float* __restrict__ states,
    const float* __restrict__ c1b, const float* __restrict__ c2b,
    const float* __restrict__ cfw, const float* __restrict__ cfb,
    const u16* __restrict__ wsb,
    u16* __restrict__ c2g,
    u16* __restrict__ ctxg)
{
  __shared__ float s_st[8][96];
  __shared__ __align__(16) u16 act1[8*108*16];
  __shared__ float s_cf[64][25];

  const int tid  = threadIdx.x;
  const int lane = tid & 63;
  const int w    = tid >> 6;
  const int arow = lane & 15;
  const int grp  = lane >> 4;
  const int m0   = blockIdx.x * 8;

  bf16x8 Bc1 = *(const bf16x8*)(wsb + W1C_OFF + arow*32 + grp*8);
  bf16x8 b2f[5][2];
  #pragma unroll
  for (int p = 0; p < 5; p++)
    #pragma unroll
    for (int nt = 0; nt < 2; nt++)
      b2f[p][nt] = *(const bf16x8*)(wsb + W2_OFF + (nt*16 + arow)*160 + p*32 + grp*8);
  float c1bv[4], c2bv0[4], c2bv1[4];
  #pragma unroll
  for (int r = 0; r < 4; r++) {
    c1bv[r]  = c1b[grp*4 + r];
    c2bv0[r] = c2b[grp*4 + r];
    c2bv1[r] = c2b[16 + grp*4 + r];
  }
  const float cfbr = cfb[lane];

  if (tid < 376) {
    float2 v = *(const float2*)(states + (size_t)m0*94 + tid*2);
    int s = (tid*2)/94, c = (tid*2)%94;
    *(float2*)&s_st[s][c] = v;
  }
  for (int i = tid; i < 608; i += 512) {
    int s = i / 76; int r = i - s*76; int hi2 = r >> 1; int h = r & 1;
    int hp;
    if (hi2 < 12)      hp = hi2;
    else if (hi2 < 24) hp = 96 + (hi2 - 12);
    else if (hi2 < 31) hp = (hi2 - 23) * 12;
    else               hp = (hi2 - 30) * 12 + 11;
    u32 a = (u32)((s*108 + hp)*32 + h*16) ^ (u32)((hp & 7) << 4);
    *(uint4*)((char*)act1 + a) = (uint4){0,0,0,0};
  }
  for (int i = tid; i < 1536; i += 512) s_cf[i/24][i%24] = cfw[i];
  __syncthreads();

  const bf16x8 zv = {0,0,0,0,0,0,0,0};

  for (int mt = w; mt < 35; mt += 8) {
    int row = mt*16 + arow;
    int s = (int)(((u32)row * 59919u) >> 22); int pos = row - s*70;
    int y = (int)(((u32)pos * 6554u) >> 16);  int x = pos - y*10;
    bf16x8 pf = zv;
    if (grp == 0) {
      const float* gs = &s_st[s][0];
      #pragma unroll
      for (int t = 0; t < 8; t++) {
        int dy = t/3, dx = t - (t/3)*3;
        int yy = y + dy - 1, xx = x + dx - 1;
        bool ok = (yy >= 0) & (yy < 7) & (xx >= 0) & (xx < 10);
        float v = gs[ok ? yy*10 + xx : 0];
        pf[t] = (short)f2bf(ok ? v : 0.f);
      }
    } else if (grp == 1) {
      int yy = y + 1, xx = x + 1;
      bool ok = (yy < 7) & (xx < 10);
      float v = s_st[s][ok ? yy*10 + xx : 0];
      pf[0] = (short)f2bf(ok ? v : 0.f);
    }
    f32x4 acc = __builtin_amdgcn_mfma_f32_16x16x32_bf16(Bc1, pf, (f32x4){0.f,0.f,0.f,0.f}, 0, 0, 0);
    int hp = (y+1)*12 + (x+1);
    u16 q0 = f2bf(fmaxf(acc[0] + c1bv[0], 0.f));
    u16 q1 = f2bf(fmaxf(acc[1] + c1bv[1], 0.f));
    u16 q2 = f2bf(fmaxf(acc[2] + c1bv[2], 0.f));
    u16 q3 = f2bf(fmaxf(acc[3] + c1bv[3], 0.f));
    u64 pk = (u64)q0 | ((u64)q1 << 16) | ((u64)q2 << 32) | ((u64)q3 << 48);
    u32 wa = (u32)(((s*108 + hp)*16 + grp*4)*2) ^ (u32)((hp & 7) << 4);
    *(u64*)((char*)act1 + wa) = pk;
  }
  __syncthreads();

  for (int mt = w; mt < 35; mt += 8) {
    int row = mt*16 + arow;
    int s = (int)(((u32)row * 59919u) >> 22); int pos = row - s*70;
    int y = (int)(((u32)pos * 6554u) >> 16);  int x = pos - y*10;
    f32x4 acc0 = {0.f,0.f,0.f,0.f}, acc1 = {0.f,0.f,0.f,0.f};
    #pragma unroll
    for (int p = 0; p < 5; p++) {
      int tap = p*2 + (grp >> 1); if (tap > 8) tap = 8;
      int dy = (tap * 11) >> 5; int dx = tap - dy*3;
      int hp = (y + dy)*12 + (x + dx);
      u32 ra = (u32)(((s*108 + hp)*16 + (grp & 1)*8)*2) ^ (u32)((hp & 7) << 4);
      bf16x8 bv = *(const bf16x8*)((const char*)act1 + ra);
      acc0 = __builtin_amdgcn_mfma_f32_16x16x32_bf16(b2f[p][0], bv, acc0, 0, 0, 0);
      acc1 = __builtin_amdgcn_mfma_f32_16x16x32_bf16(b2f[p][1], bv, acc1, 0, 0, 0);
    }
    {
      u16 q0 = f2bf(fmaxf(acc0[0] + c2bv0[0], 0.f));
      u16 q1 = f2bf(fmaxf(acc0[1] + c2bv0[1], 0.f));
      u16 q2 = f2bf(fmaxf(acc0[2] + c2bv0[2], 0.f));
      u16 q3 = f2bf(fmaxf(acc0[3] + c2bv0[3], 0.f));
      u64 pk = (u64)q0 | ((u64)q1 << 16) | ((u64)q2 << 32) | ((u64)q3 << 48);
      *(u64*)(c2g + (size_t)(m0 + s)*2240 + pos*32 + grp*4) = pk;
    }
    {
      u16 q0 = f2bf(fmaxf(acc1[0] + c2bv1[0], 0.f));
      u16 q1 = f2bf(fmaxf(acc1[1] + c2bv1[1], 0.f));
      u16 q2 = f2bf(fmaxf(acc1[2] + c2bv1[2], 0.f));
      u16 q3 = f2bf(fmaxf(acc1[3] + c2bv1[3], 0.f));
      u64 pk = (u64)q0 | ((u64)q1 << 16) | ((u64)q2 << 32) | ((u64)q3 << 48);
      *(u64*)(c2g + (size_t)(m0 + s)*2240 + pos*32 + 16 + grp*4) = pk;
    }
  }

  {
    float a = cfbr;
    #pragma unroll
    for (int k = 0; k < 24; k++) a = fmaf(s_cf[lane][k], s_st[w][70 + k], a);
    ctxg[(size_t)(m0 + w)*64 + lane] = f2bf(fmaxf(a, 0.f));
  }
}

// ---------------------------------------------------------------------------
// K1b v2: 64-sample tile, 512 blocks/chunk (2/CU), 4M x 2N wave tiling.
// B LDS reads per ks: 32/block (was 64). Trunk epilogue read/write split.
// ---------------------------------------------------------------------------
__global__ __launch_bounds__(512, 2) void k_gemm(
    const u16* __restrict__ c2g, const u16* __restrict__ ctxg,
    const float* __restrict__ gfb, const float* __restrict__ tbv,
    const u16* __restrict__ wsb, u16* __restrict__ trunk_ws, int nbase)
{
  __shared__ __align__(16) u16 s_b[2][128*36];   // 18.4 KB
  __shared__ __align__(16) u16 s_g[64*204];      // 26.1 KB

  const int tid  = threadIdx.x;
  const int lane = tid & 63;
  const int w    = tid >> 6;
  const int arow = lane & 15;
  const int grp  = lane >> 4;
  const int wm   = w & 3;         // M-tile (16 rows)
  const int wn   = w >> 2;        // N-half (4 nt)
  const int m0   = blockIdx.x * 64;

  float gfbv[4], tbvv[4];
  #pragma unroll
  for (int q = 0; q < 4; q++) {
    gfbv[q] = gfb[(wn*4 + q)*16 + arow];
    tbvv[q] = tbv[(wn*4 + q)*16 + arow];
  }

  const int srow = tid >> 2, sseg = (tid & 3) * 8;
  const u16* wg = wsb + WG_OFF;
  const u16* ap = c2g + (size_t)(m0 + wm*16 + arow) * 2240 + grp*8;

  {
    uint4 b0 = *(const uint4*)(wg + (size_t)srow*2240 + sseg);
    *(uint4*)&s_b[0][srow*36 + sseg] = b0;
  }
  bf16x8 a_cur = *(const bf16x8*)(ap);
  bf16x8 a_nxt = *(const bf16x8*)(ap + 32);
  f32x4 acc[4];
  #pragma unroll
  for (int q = 0; q < 4; q++) acc[q] = (f32x4){0.f,0.f,0.f,0.f};
  __syncthreads();

  #pragma unroll 2
  for (int ks = 0; ks < 70; ks++) {
    uint4 bnew;
    if (ks < 69)
      bnew = *(const uint4*)(wg + (size_t)srow*2240 + (ks+1)*32 + sseg);
    bf16x8 a_fut = a_nxt;
    if (ks < 68)
      a_fut = *(const bf16x8*)(ap + (size_t)(ks+2)*32);
    const u16* sb = &s_b[ks & 1][0];
    #pragma unroll
    for (int q = 0; q < 4; q++) {
      bf16x8 bv = *(const bf16x8*)&sb[((wn*4 + q)*16 + arow)*36 + grp*8];
      acc[q] = __builtin_amdgcn_mfma_f32_16x16x32_bf16(a_cur, bv, acc[q], 0, 0, 0);
    }
    if (ks < 69)
      *(uint4*)&s_b[(ks+1) & 1][srow*36 + sseg] = bnew;
    a_cur = a_nxt; a_nxt = a_fut;
    bar_lds();
  }

  // grid_fc -> s_g cols (wn half), + ctx cols 128..191
  #pragma unroll
  for (int q = 0; q < 4; q++)
    #pragma unroll
    for (int r = 0; r < 4; r++)
      s_g[(wm*16 + grp*4 + r)*204 + (wn*4 + q)*16 + arow] = f2bf(fmaxf(acc[q][r] + gfbv[q], 0.f));
  {
    int row = tid >> 3, seg = (tid & 7) * 8;
    uint4 c0 = *(const uint4*)(ctxg + (size_t)(m0 + row)*64 + seg);
    *(uint4*)&s_g[row*204 + 128 + seg] = c0;
  }
  bar_lds();

  // trunk: read into regs, barrier, then write (cross-wave in-place hazard)
  f32x4 tacc[4];
  #pragma unroll
  for (int q = 0; q < 4; q++) tacc[q] = (f32x4){0.f,0.f,0.f,0.f};
  #pragma unroll
  for (int ks = 0; ks < 6; ks++) {
    bf16x8 av = *(const bf16x8*)&s_g[(wm*16 + arow)*204 + ks*32 + grp*8];
    #pragma unroll
    for (int q = 0; q < 4; q++) {
      bf16x8 bv = *(const bf16x8*)(wsb + WT_OFF + (size_t)((wn*4 + q)*16 + arow)*192 + ks*32 + grp*8);
      tacc[q] = __builtin_amdgcn_mfma_f32_16x16x32_bf16(av, bv, tacc[q], 0, 0, 0);
    }
  }
  bar_lds();
  #pragma unroll
  for (int q = 0; q < 4; q++)
    #pragma unroll
    for (int r = 0; r < 4; r++)
      s_g[(wm*16 + grp*4 + r)*204 + (wn*4 + q)*16 + arow] = f2bf(fmaxf(tacc[q][r] + tbvv[q], 0.f));
  bar_lds();

  // store 64x128 trunk tile (64-aligned m0 never crosses a b boundary)
  {
    const int t0 = (nbase + m0) & 127;
    const int bb = (nbase + m0) >> 7;
    int row = tid >> 3, seg = (tid & 7) * 16;
    #pragma unroll
    for (int j = 0; j < 2; j++) {
      uint4 v = *(const uint4*)&s_g[row*204 + seg + j*8];
      *(uint4*)(trunk_ws + ((size_t)(t0 + row)*B_ + bb)*128 + seg + j*8) = v;
    }
  }
}

// ---------------------------------------------------------------------------
// K1c: k_xg (verbatim R12 — [t][b][512] layout).
// ---------------------------------------------------------------------------
__global__ __launch_bounds__(512, 2) void k_xg(
    const u16* __restrict__ trunk_ws, const u16* __restrict__ wsb,
    u16* __restrict__ gxg)
{
  const int tid  = threadIdx.x;
  const int lane = tid & 63;
  const int w    = tid >> 6;
  const int arow = lane & 15;
  const int grp  = lane >> 4;
  const int t    = blockIdx.x >> 3;
  const int bch  = (blockIdx.x & 7) * 128;
  const int samp = bch + w*16 + arow;

  bf16x8 bv[4];
  #pragma unroll
  for (int ks = 0; ks < 4; ks++)
    bv[ks] = *(const bf16x8*)(trunk_ws + ((size_t)t*B_ + samp)*128 + ks*32 + grp*8);

  const u16* wip = wsb + WIH_OFF;
  u16* gout = gxg + ((size_t)t*B_ + samp)*512;

  #pragma unroll 1
  for (int ntb = 0; ntb < 32; ntb += 4) {
    f32x4 acc[4];
    #pragma unroll
    for (int q = 0; q < 4; q++) acc[q] = (f32x4){0.f,0.f,0.f,0.f};
    #pragma unroll
    for (int ks = 0; ks < 4; ks++) {
      #pragma unroll
      for (int q = 0; q < 4; q++) {
        bf16x8 aw = *(const bf16x8*)(wip + (size_t)((ntb+q)*16 + arow)*128 + ks*32 + grp*8);
        acc[q] = __builtin_amdgcn_mfma_f32_16x16x32_bf16(aw, bv[ks], acc[q], 0, 0, 0);
      }
    }
    #pragma unroll
    for (int q = 0; q < 4; q++) {
      u16 q0 = f2bf(acc[q][0]);
      u16 q1 = f2bf(acc[q][1]);
      u16 q2 = f2bf(acc[q][2]);
      u16 q3 = f2bf(acc[q][3]);
      u64 pk = (u64)q0 | ((u64)q1 << 16) | ((u64)q2 << 32) | ((u64)q3 << 48);
      *(u64*)(gout + (ntb+q)*16 + grp*4) = pk;
    }
  }
}

// ---------------------------------------------------------------------------
// K2: MFMA LSTM v5. Gate redistribution via intra-wave shuffles (no s_g,
// ONE barrier/step). Cell thread: (sample=grp, h=w*16+arow).
// ---------------------------------------------------------------------------
__global__ __launch_bounds__(512, 1) void k_lstm(
    const u16* __restrict__ gxg, const float* __restrict__ whh,
    const float* __restrict__ bih, u16* __restrict__ h_ws)
{
  __shared__ __align__(16) u16 s_h[2][16*136];   // rows 4..15 stay zero

  const int tid  = threadIdx.x;
  const int lane = tid & 63;
  const int w    = tid >> 6;
  const int arow = lane & 15;
  const int grp  = lane >> 4;
  const int b0   = blockIdx.x * 4;

  bf16x8 Bv[4][4];
  float bihv[4];
  #pragma unroll
  for (int j = 0; j < 4; j++) {
    const int row = j*128 + w*16 + arow;
    bihv[j] = bih[row];
    #pragma unroll
    for (int ks = 0; ks < 4; ks++) {
      const float* s1 = whh + (size_t)row*128 + ks*32 + grp*8;
      float4 a0 = *(const float4*)s1, a1 = *(const float4*)(s1 + 4);
      bf16x8 t1;
      t1[0]=(short)f2bf(a0.x); t1[1]=(short)f2bf(a0.y); t1[2]=(short)f2bf(a0.z); t1[3]=(short)f2bf(a0.w);
      t1[4]=(short)f2bf(a1.x); t1[5]=(short)f2bf(a1.y); t1[6]=(short)f2bf(a1.z); t1[7]=(short)f2bf(a1.w);
      Bv[j][ks] = t1;
    }
  }

  for (int i = tid; i < 2*16*136; i += 512) ((u16*)s_h)[i] = 0;

  // this thread's cell: sample grp, h = w*16 + arow
  const u16* gxb = gxg + ((size_t)(b0 + grp))*512 + w*16 + arow;   // + t*B*512 + j*128
  u16 Gc[4], Gn[4];
  #pragma unroll
  for (int j = 0; j < 4; j++) {
    Gc[j] = gxb[(size_t)0*B_*512 + j*128];
    Gn[j] = gxb[(size_t)1*B_*512 + j*128];
  }

  const int prow = tid >> 4, pseg = (tid & 15) * 8;   // tid<64 copy-out cohort
  float cst = 0.f;
  __syncthreads();

  for (int t = 0; t < T_; t++) {
    const int p = t & 1;

    u16 Gf[4] = {0,0,0,0};
    if (t + 2 < T_) {
      #pragma unroll
      for (int j = 0; j < 4; j++)
        Gf[j] = gxb[(size_t)(t+2)*B_*512 + j*128];
    }
    if (t > 0 && tid < 64) {
      uint4 hv = *(const uint4*)&s_h[p][prow*136 + pseg];
      *(uint4*)(h_ws + ((size_t)(t-1)*B_ + b0 + prow)*128 + pseg) = hv;
    }

    // recurrent MFMA
    f32x4 racc[4];
    #pragma unroll
    for (int j = 0; j < 4; j++) racc[j] = (f32x4){0.f,0.f,0.f,0.f};
    #pragma unroll
    for (int ks = 0; ks < 4; ks++) {
      bf16x8 av = *(const bf16x8*)&s_h[p][arow*136 + ks*32 + grp*8];
      #pragma unroll
      for (int j = 0; j < 4; j++)
        racc[j] = __builtin_amdgcn_mfma_f32_16x16x32_bf16(av, Bv[j][ks], racc[j], 0, 0, 0);
    }

    // intra-wave redistribute: lane needs racc[j][grp] from lane arow
    float g4[4];
    #pragma unroll
    for (int j = 0; j < 4; j++) {
      float t0v = __shfl(racc[j][0], arow);
      float t1v = __shfl(racc[j][1], arow);
      float t2v = __shfl(racc[j][2], arow);
      float t3v = __shfl(racc[j][3], arow);
      g4[j] = (grp == 0) ? t0v : (grp == 1) ? t1v : (grp == 2) ? t2v : t3v;
    }

    // one cell per thread
    {
      float xi = g4[0] + bf2f(Gc[0]) + bihv[0];
      float xf = g4[1] + bf2f(Gc[1]) + bihv[1];
      float xg = g4[2] + bf2f(Gc[2]) + bihv[2];
      float xo = g4[3] + bf2f(Gc[3]) + bihv[3];
      float I = sigm(xi), F = sigm(xf), O = sigm(xo), G = tanh_f(xg);
      cst = F*cst + I*G;
      float hvv = O * tanh_f(cst);
      s_h[1-p][grp*136 + w*16 + arow] = f2bf(hvv);
    }

    #pragma unroll
    for (int j = 0; j < 4; j++) { Gc[j] = Gn[j]; Gn[j] = Gf[j]; }
    bar_lds();
  }

  if (tid < 64) {
    uint4 hv = *(const uint4*)&s_h[T_ & 1][prow*136 + pseg];
    *(uint4*)(h_ws + ((size_t)(T_-1)*B_ + b0 + prow)*128 + pseg) = hv;
  }
}

// ---------------------------------------------------------------------------
// K3: heads (verbatim — known good).
// ---------------------------------------------------------------------------
__global__ __launch_bounds__(256, 1) void k_heads(
    const u16* __restrict__ h_ws, const int* __restrict__ actions,
    const float* __restrict__ aw, const float* __restrict__ ab,
    const float* __restrict__ cw, const float* __restrict__ cb,
    float* __restrict__ out)
{
  const int tid  = threadIdx.x;
  const int lane = tid & 63;
  const int w    = tid >> 6;
  const int arow = lane & 15;
  const int grp  = lane >> 4;

  bf16x8 Ah[4];
  #pragma unroll
  for (int ks = 0; ks < 4; ks++) {
    bf16x8 v = {0,0,0,0,0,0,0,0};
    if (arow < 4) {
      const float* src = aw + arow*128 + ks*32 + grp*8;
      #pragma unroll
      for (int j = 0; j < 8; j++) v[j] = (short)f2bf(src[j]);
    } else if (arow == 4) {
      const float* src = cw + ks*32 + grp*8;
      #pragma unroll
      for (int j = 0; j < 8; j++) v[j] = (short)f2bf(src[j]);
    }
    Ah[ks] = v;
  }
  const float ab0=ab[0], ab1=ab[1], ab2=ab[2], ab3=ab[3], cb0=cb[0];

  #pragma unroll
  for (int g = 0; g < 4; g++) {
    int m0 = (blockIdx.x*4 + w)*64 + g*16;
    int t  = m0 >> 10; int bb = m0 & 1023;
    f32x4 acc = {0.f,0.f,0.f,0.f};
    #pragma unroll
    for (int ks = 0; ks < 4; ks++) {
      bf16x8 bv = *(const bf16x8*)(h_ws + ((size_t)t*B_ + bb + arow)*128 + ks*32 + grp*8);
      acc = __builtin_amdgcn_mfma_f32_16x16x32_bf16(Ah[ks], bv, acc, 0, 0, 0);
    }
    float cr = __shfl_xor(acc[0], 16);
    if (grp == 0) {
      float L0 = acc[0] + ab0, L1 = acc[1] + ab1, L2 = acc[2] + ab2, L3 = acc[3] + ab3;
      float Lv = cr + cb0;
      float mm = fmaxf(fmaxf(L0, L1), fmaxf(L2, L3));
      float e0 = __expf(L0-mm), e1 = __expf(L1-mm), e2 = __expf(L2-mm), e3 = __expf(L3-mm);
      float S = e0+e1+e2+e3; float lse = __logf(S);
      float p0=L0-mm-lse, p1=L1-mm-lse, p2=L2-mm-lse, p3=L3-mm-lse;
      int n = (bb + arow)*T_ + t;
      int a = actions[n];
      float lpa = (a==0)?p0:(a==1)?p1:(a==2)?p2:p3;
      float ent = -(e0*p0 + e1*p1 + e2*p2 + e3*p3) / S;
      out[n] = lpa; out[NBT + n] = Lv; out[2*NBT + n] = ent;
    }
  }
}

extern "C" void kernel_launch(void* const* d_in, const int* in_sizes, int n_in,
                              void* d_out, int out_size, void* d_ws, size_t ws_size,
                              hipStream_t stream) {
  const float* states = (const float*)d_in[0];
  const int*   actions= (const int*)  d_in[1];
  const float* c1w = (const float*)d_in[2];
  const float* c1b = (const float*)d_in[3];
  const float* c2w = (const float*)d_in[4];
  const float* c2b = (const float*)d_in[5];
  const float* gfw = (const float*)d_in[6];
  const float* gfb = (const float*)d_in[7];
  const float* cfw = (const float*)d_in[8];
  const float* cfb = (const float*)d_in[9];
  const float* tw  = (const float*)d_in[10];
  const float* tbv = (const float*)d_in[11];
  const float* wih = (const float*)d_in[12];
  const float* bih = (const float*)d_in[13];
  const float* whh = (const float*)d_in[14];
  const float* aw  = (const float*)d_in[15];
  const float* ab  = (const float*)d_in[16];
  const float* cw  = (const float*)d_in[17];
  const float* cb  = (const float*)d_in[18];
  float* out = (float*)d_out;

  u16* wsb   = (u16*)d_ws;
  u16* trunk = (u16*)((char*)d_ws + TRUNK_OFF);
  u16* h_ws  = (u16*)((char*)d_ws + H_OFF);
  u16* ctxg  = (u16*)((char*)d_ws + CTX_OFF);
  u16* c2g   = (u16*)((char*)d_ws + C2_OFF);
  u16* gxg   = (u16*)((char*)d_ws + GX_OFF);

  k_cvt<<<(CVT_TOTAL + 255)/256, 256, 0, stream>>>(gfw, tw, wih, c2w, c1w, wsb);

  for (int c = 0; c < NCHUNK; c++) {
    const float* st_c = states + (size_t)c * CHUNK * 94;
    u16* ctx_c = ctxg + (size_t)c * CHUNK * 64;
    k_conv<<<CHUNK/8, 512, 0, stream>>>(st_c, c1b, c2b, cfw, cfb, wsb, c2g, ctx_c);
    k_gemm<<<CHUNK/64, 512, 0, stream>>>(c2g, ctx_c, gfb, tbv, wsb, trunk, c*CHUNK);
  }
  k_xg<<<T_*8, 512, 0, stream>>>(trunk, wsb, gxg);
  k_lstm<<<B_/4, 512, 0, stream>>>(gxg, whh, bih, h_ws);
  k_heads<<<512, 256, 0, stream>>>(h_ws, actions, aw, ab, cw, cb, out);
}